// Round 8
// baseline (160.756 us; speedup 1.0000x reference)
//
#include <hip/hip_runtime.h>

// ---------------------------------------------------------------------------
// attention_76089640615954 on MI355X (gfx950)
// x:[1,256,64,64] -> 1x1 conv (3C) -> 11x11 depthwise -> 8-head attn (N=4096,
// d=32, temp=5) -> 1x1 conv + bias -> relu + residual.
// fp16 MFMA (16x16x32), fp32 accumulate, fixed-shift softmax (Cauchy-Schwarz
// bound by k_norms; exp2 shift rides in the score-MFMA C-operand).
// R7 evidence: staged global_load_lds + __syncthreads (vmcnt(0) drain) never
// overlapped load with compute -> ~40us. R3's barrier-free direct-load loop
// hid latency fine; its cost scaled with unique K/V traffic.
// R8: direct-load flash attention, q-tile 128 rows/block (8 waves x 16 rows),
// each wave owns all 4096 keys: no key split, no partials, no LDS, no
// __syncthreads. 8 waves stream identical K/V addresses; raw s_barrier every
// 4 iters keeps the convoy in the 32KB L1 window => unique L2 traffic 128MB,
// head-pinned per XCD (bid&7). k_norm_o/o_part deleted; prep_w merged into
// k_prep (8 -> 6 kernels).
// ---------------------------------------------------------------------------

typedef _Float16 f16;
typedef __fp16 hf16x2 __attribute__((ext_vector_type(2)));
typedef _Float16 f16x8 __attribute__((ext_vector_type(8)));
typedef float f32x4 __attribute__((ext_vector_type(4)));

#define HW 4096      // 64*64 pixels
#define NC 256       // channels

#if __has_builtin(__builtin_amdgcn_exp2f)
#define EXP2(x) __builtin_amdgcn_exp2f(x)
#else
#define EXP2(x) exp2f(x)
#endif

static __device__ __forceinline__ f32x4 mfma16(f16x8 a, f16x8 b, f32x4 c) {
  return __builtin_amdgcn_mfma_f32_16x16x32_f16(a, b, c, 0, 0, 0);
}

// -------------- prep: x -> xt[p][c] fp16, weights -> fp16 ------------------
__global__ __launch_bounds__(256) void k_prep(
    const float* __restrict__ x, f16* __restrict__ xt,
    const float* __restrict__ wpw, const float* __restrict__ wlin,
    f16* __restrict__ wpw_h, f16* __restrict__ wlin_h,
    int* __restrict__ kmax_bits) {
  __shared__ float t[32][33];
  int b = blockIdx.x;
  if (b < 1024) {
    int bc = b >> 7;     // 8 channel tiles of 32
    int bp = b & 127;    // 128 pixel tiles of 32
    int tx = threadIdx.x & 31, ty = threadIdx.x >> 5;  // ty 0..7
#pragma unroll
    for (int i = 0; i < 4; i++) {
      int c = bc * 32 + ty + i * 8;
      t[ty + i * 8][tx] = x[c * HW + bp * 32 + tx];
    }
    __syncthreads();
#pragma unroll
    for (int i = 0; i < 4; i++) {
      int p = bp * 32 + ty + i * 8;
      xt[p * NC + bc * 32 + tx] = (f16)t[tx][ty + i * 8];
    }
  } else {
    int i = (b - 1024) * 256 + threadIdx.x;  // 32768 threads
    if (i < 8) kmax_bits[i] = 0;             // init for k_norms' atomicMax
    for (int idx = i; idx < 3 * NC * NC; idx += 32768)
      wpw_h[idx] = (f16)wpw[idx];
    for (int idx = i; idx < NC * NC; idx += 32768)
      wlin_h[idx] = (f16)wlin[idx];
  }
}

// ------------------- GEMM1: qkv = Wpw[768,256] * x  (+bias) ----------------
__global__ __launch_bounds__(256) void k_gemm_qkv(
    const f16* __restrict__ w, const f16* __restrict__ xt,
    const float* __restrict__ bias, float* __restrict__ out) {
  int bm = blockIdx.x >> 6;   // 12
  int bn = blockIdx.x & 63;   // 64
  int wave = threadIdx.x >> 6, lane = threadIdx.x & 63;
  int r = lane & 15, g = lane >> 4;
  int m_row = bm * 64 + wave * 16 + r;
  int n0 = bn * 64;
  f32x4 acc[4] = {};
  for (int kk = 0; kk < NC; kk += 32) {
    f16x8 a = *(const f16x8*)&w[m_row * NC + kk + g * 8];
#pragma unroll
    for (int nt = 0; nt < 4; nt++) {
      f16x8 b = *(const f16x8*)&xt[(n0 + nt * 16 + r) * NC + kk + g * 8];
      acc[nt] = mfma16(a, b, acc[nt]);
    }
  }
  int mbase = bm * 64 + wave * 16 + g * 4;
  float bj[4];
#pragma unroll
  for (int j = 0; j < 4; j++) bj[j] = bias[mbase + j];
#pragma unroll
  for (int nt = 0; nt < 4; nt++)
#pragma unroll
    for (int j = 0; j < 4; j++)
      out[(mbase + j) * HW + n0 + nt * 16 + r] = acc[nt][j] + bj[j];
}

// ------------------- depthwise 11x11, pad 5, groups=768 --------------------
// q is pre-scaled by (1/temp)*log2(e) so softmax runs natively base-2.
__global__ __launch_bounds__(256) void k_dwconv(
    const float* __restrict__ qkv, const float* __restrict__ wdw,
    const float* __restrict__ bdw, f16* __restrict__ q_nm,
    f16* __restrict__ k_nm, f16* __restrict__ v_cm) {
  __shared__ float img[74 * 74];
  __shared__ float wgt[121];
  int c = blockIdx.x;
  int tid = threadIdx.x;
  for (int i = tid; i < 74 * 74; i += 256) {
    int row = i / 74, col = i - row * 74;
    int y = row - 5, xx = col - 5;
    img[i] = ((unsigned)y < 64u && (unsigned)xx < 64u) ? qkv[c * HW + y * 64 + xx]
                                                       : 0.f;
  }
  for (int i = tid; i < 121; i += 256) wgt[i] = wdw[c * 121 + i];
  __syncthreads();
  float bias = bdw[c];
#pragma unroll
  for (int it = 0; it < 2; it++) {
    int gi = it * 256 + tid;
    int px0 = gi * 8;
    int y = px0 >> 6, x0 = px0 & 63;
    float acc[8] = {};
#pragma unroll
    for (int ky = 0; ky < 11; ky++) {
      const float* rp = &img[(y + ky) * 74 + x0];
      float rv[18];
#pragma unroll
      for (int t = 0; t < 18; t++) rv[t] = rp[t];
#pragma unroll
      for (int kx = 0; kx < 11; kx++) {
        float wv = wgt[ky * 11 + kx];
#pragma unroll
        for (int p = 0; p < 8; p++) acc[p] = fmaf(rv[kx + p], wv, acc[p]);
      }
    }
    if (c < 256) {
      int h = c >> 5, d = c & 31;
#pragma unroll
      for (int p = 0; p < 8; p++)
        q_nm[(h * HW + px0 + p) * 32 + d] =
            (f16)((acc[p] + bias) * 0.28853900817779268f);  // 0.2*log2(e)
    } else if (c < 512) {
      int cc = c - 256;
      int h = cc >> 5, d = cc & 31;
#pragma unroll
      for (int p = 0; p < 8; p++)
        k_nm[(h * HW + px0 + p) * 32 + d] = (f16)(acc[p] + bias);
    } else {
      int cc = c - 512;
#pragma unroll
      for (int p = 0; p < 8; p++)
        v_cm[cc * HW + px0 + p] = (f16)(acc[p] + bias);
    }
  }
}

// ---------------- norms: ||q_row|| per row, max ||k_row|| per head ---------
__global__ __launch_bounds__(256) void k_norms(
    const f16* __restrict__ q_nm, const f16* __restrict__ k_nm,
    float* __restrict__ q_bound, int* __restrict__ kmax_bits) {
  __shared__ float red[256];
  int b = blockIdx.x, t = threadIdx.x;
  const f16* src = (b < 128) ? q_nm : k_nm;
  int row = ((b & 127) * 256) + t;
  const f16x8* p = (const f16x8*)&src[row * 32];
  float s = 0.f;
#pragma unroll
  for (int i = 0; i < 4; i++) {
    f16x8 v = p[i];
#pragma unroll
    for (int j = 0; j < 8; j++) {
      float f = (float)v[j];
      s = fmaf(f, f, s);
    }
  }
  float nrm = sqrtf(s);
  if (b < 128) {
    q_bound[row] = nrm;
  } else {
    red[t] = nrm;
    __syncthreads();
    for (int off = 128; off > 0; off >>= 1) {
      if (t < off) red[t] = fmaxf(red[t], red[t + off]);
      __syncthreads();
    }
    if (t == 0) atomicMax(&kmax_bits[row >> 12], __float_as_int(red[0]));
  }
}

// ----------------------------- flash attention -----------------------------
// Block = 512 threads = 8 waves; q-tile = 128 rows (wave wv owns rows
// [qt*128+wv*16, +16) x ALL 4096 keys). No LDS, no __syncthreads, no
// partials: each wave normalizes and writes its own rows. The 8 waves
// stream identical K/V addresses; raw s_barrier every 4 iters bounds the
// convoy drift so trailing waves hit L1. Fixed-shift softmax: P =
// exp2(s - C_row) with -C in the score-MFMA C-operand (Cauchy-Schwarz bound,
// P <= 2^13.9 f16-safe, 2^C cancels in O/L). Scores transposed: S^T =
// mfma(A=K row-permuted pr(i)=8*(i>>2)+(i&3), B=Q) so score C/D layout ==
// PV A-fragment layout; P never leaves registers.
// Block swizzle: h = bid&7 -> each XCD serves one head (512KB L2-resident).
__global__ __launch_bounds__(512, 2) void k_attn(
    const f16* __restrict__ q_nm, const f16* __restrict__ k_nm,
    const f16* __restrict__ v_cm, const float* __restrict__ q_bound,
    const int* __restrict__ kmax_bits, f16* __restrict__ newx) {
  int h = blockIdx.x & 7;    // head-affine swizzle
  int qt = blockIdx.x >> 3;  // 32 q tiles of 128 rows
  int wv = threadIdx.x >> 6, lane = threadIdx.x & 63;
  int r = lane & 15, g = lane >> 4;
  int n_base = qt * 128 + wv * 16;
  const f16* qh = q_nm + h * (HW * 32);
  const f16* kh = k_nm + h * (HW * 32);
  const f16* vh = v_cm + h * (32 * HW);

  f16x8 bq = *(const f16x8*)&qh[(n_base + r) * 32 + g * 8];
  float kmax = __int_as_float(kmax_bits[h]);
  float mC = 13.9f - q_bound[h * HW + n_base + r] * kmax;
  f32x4 cinit = {mC, mC, mC, mC};
  int pr = ((r & 12) << 1) | (r & 3);  // 8*(r>>2)+(r&3)
  f32x4 acc0 = {0.f, 0.f, 0.f, 0.f}, acc1 = {0.f, 0.f, 0.f, 0.f};
  float L = 0.f;

  const f16* kp = kh + pr * 32 + g * 8;
  const f16* vp0 = vh + r * HW + g * 8;
  const f16* vp1 = vp0 + 16 * HW;

  for (int it = 0; it < 32; ++it) {
#pragma unroll
    for (int s = 0; s < 4; ++s) {
      f16x8 ak0 = *(const f16x8*)(kp);
      f16x8 ak1 = *(const f16x8*)(kp + 128);
      f16x8 bv0 = *(const f16x8*)(vp0);
      f16x8 bv1 = *(const f16x8*)(vp1);
      kp += 1024;  // 32 keys * 32 d
      vp0 += 32;
      vp1 += 32;
      // scores (pre-shifted): sX[j] = S[key 32it'+8g+j(+4)][row n_base+r] - C
      f32x4 s0 = mfma16(ak0, bq, cinit);
      f32x4 s1 = mfma16(ak1, bq, cinit);
      float p[8];
#pragma unroll
      for (int j = 0; j < 4; j++) {
        p[j] = EXP2(s0[j]);
        p[4 + j] = EXP2(s1[j]);
      }
      L += ((p[0] + p[1]) + (p[2] + p[3])) + ((p[4] + p[5]) + (p[6] + p[7]));
      union { hf16x2 h2[4]; f16x8 v; } u;
#pragma unroll
      for (int j = 0; j < 4; j++)
        u.h2[j] = __builtin_amdgcn_cvt_pkrtz(p[2 * j], p[2 * j + 1]);
      acc0 = mfma16(u.v, bv0, acc0);
      acc1 = mfma16(u.v, bv1, acc1);
    }
    __builtin_amdgcn_s_barrier();  // convoy cohesion (no vmcnt drain)
  }
  // ---- normalize and write own rows (no cross-wave combine needed) ----
  L += __shfl_xor(L, 16);
  L += __shfl_xor(L, 32);
  float il = 1.f / L;
#pragma unroll
  for (int j = 0; j < 4; j++) {
    float ilj = __shfl(il, 4 * g + j);  // 1/L for out-row n_base+4g+j
    int n = n_base + 4 * g + j;
    newx[n * NC + h * 32 + r] = (f16)(acc0[j] * ilj);
    newx[n * NC + h * 32 + 16 + r] = (f16)(acc1[j] * ilj);
  }
}

// ---------- GEMM2: out = relu(Wlin[256,256] * newx + b) + x ----------------
__global__ __launch_bounds__(256) void k_gemm_proj(
    const f16* __restrict__ w, const f16* __restrict__ nx,
    const float* __restrict__ bias, const float* __restrict__ x,
    float* __restrict__ out) {
  int bm = blockIdx.x >> 6;  // 4
  int bn = blockIdx.x & 63;  // 64
  int wave = threadIdx.x >> 6, lane = threadIdx.x & 63;
  int r = lane & 15, g = lane >> 4;
  int m_row = bm * 64 + wave * 16 + r;
  int n0 = bn * 64;
  f32x4 acc[4] = {};
  for (int kk = 0; kk < NC; kk += 32) {
    f16x8 a = *(const f16x8*)&w[m_row * NC + kk + g * 8];
#pragma unroll
    for (int nt = 0; nt < 4; nt++) {
      f16x8 b = *(const f16x8*)&nx[(n0 + nt * 16 + r) * NC + kk + g * 8];
      acc[nt] = mfma16(a, b, acc[nt]);
    }
  }
  int mbase = bm * 64 + wave * 16 + g * 4;
  float bj[4];
#pragma unroll
  for (int j = 0; j < 4; j++) bj[j] = bias[mbase + j];
#pragma unroll
  for (int nt = 0; nt < 4; nt++)
#pragma unroll
    for (int j = 0; j < 4; j++) {
      int m = mbase + j, n = n0 + nt * 16 + r;
      float v = fmaxf(acc[nt][j] + bj[j], 0.f) + x[m * HW + n];
      out[m * HW + n] = v;
    }
}

// ---------------------------------------------------------------------------
extern "C" void kernel_launch(void* const* d_in, const int* in_sizes, int n_in,
                              void* d_out, int out_size, void* d_ws,
                              size_t ws_size, hipStream_t stream) {
  const float* x = (const float*)d_in[0];
  const float* w_pw = (const float*)d_in[1];
  const float* b_pw = (const float*)d_in[2];
  const float* w_dw = (const float*)d_in[3];
  const float* b_dw = (const float*)d_in[4];
  const float* w_lin = (const float*)d_in[5];
  const float* b_lin = (const float*)d_in[6];
  float* out = (float*)d_out;

  char* ws = (char*)d_ws;
  f16* wpw_h = (f16*)(ws + 0);            // 768*256*2      = 393216
  f16* wlin_h = (f16*)(ws + 393216);      // 256*256*2      = 131072
  f16* xt = (f16*)(ws + 524288);          // 4096*256*2     = 2097152
  float* qkv = (float*)(ws + 2621440);    // 768*4096*4     = 12582912
  f16* q_nm = (f16*)(ws + 15204352);      // 8*4096*32*2    = 2097152
  f16* k_nm = (f16*)(ws + 17301504);      // 2097152
  f16* v_cm = (f16*)(ws + 19398656);      // 2097152
  f16* nx = (f16*)(ws + 21495808);        // 2097152
  float* q_bound = (float*)(ws + 23592960);  // 8*4096*4    = 131072
  int* kmax_bits = (int*)(ws + 23724032);    // 32 -> total 23724064 bytes

  k_prep<<<1152, 256, 0, stream>>>(x, xt, w_pw, w_lin, wpw_h, wlin_h,
                                   kmax_bits);
  k_gemm_qkv<<<768, 256, 0, stream>>>(wpw_h, xt, b_pw, qkv);
  k_dwconv<<<768, 256, 0, stream>>>(qkv, w_dw, b_dw, q_nm, k_nm, v_cm);
  k_norms<<<256, 256, 0, stream>>>(q_nm, k_nm, q_bound, kmax_bits);
  k_attn<<<256, 512, 0, stream>>>(q_nm, k_nm, v_cm, q_bound, kmax_bits, nx);
  k_gemm_proj<<<256, 256, 0, stream>>>(wlin_h, nx, b_lin, x, out);
}

// Round 9
// 102.876 us; speedup vs baseline: 1.5626x; 1.5626x over previous
//
#include <hip/hip_runtime.h>

// ---------------------------------------------------------------------------
// attention_76089640615954 on MI355X (gfx950)
// x:[1,256,64,64] -> 1x1 conv (3C) -> 11x11 depthwise -> 8-head attn (N=4096,
// d=32, temp=5) -> 1x1 conv + bias -> relu + residual.
// fp16 MFMA (16x16x32), fp32 accumulate, fixed-shift softmax (Cauchy-Schwarz
// bound by k_norms; exp2 shift rides in the score-MFMA C-operand).
// R8 evidence: across R3/R6/R8, k_attn time == (VMEM wave-instrs per SIMD) x
// ~220cy, independent of waves/SIMD -> per-lane gather path is the serialized
// resource; only fewer VMEM instructions helps.
// R9: R7's LDS staging (correct, but serialized by __syncthreads vmcnt-drain)
// + m201-style counted-vmcnt pipeline: 4-deep 64-key chunks, 1 gload_lds per
// wave per chunk for t+2, s_waitcnt vmcnt(2) -> raw s_barrier -> compute t.
// One barrier/chunk, loads stay in flight across barriers. K bank conflict
// (8-way) fixed both-sides: slot ^= row-group on global src AND lds read.
// Per-wave VMEM 512 -> 66 instrs (8x cut).
// ---------------------------------------------------------------------------

typedef _Float16 f16;
typedef __fp16 hf16x2 __attribute__((ext_vector_type(2)));
typedef _Float16 f16x8 __attribute__((ext_vector_type(8)));
typedef float f32x4 __attribute__((ext_vector_type(4)));

#define HW 4096      // 64*64 pixels
#define NC 256       // channels

#if __has_builtin(__builtin_amdgcn_exp2f)
#define EXP2(x) __builtin_amdgcn_exp2f(x)
#else
#define EXP2(x) exp2f(x)
#endif

static __device__ __forceinline__ f32x4 mfma16(f16x8 a, f16x8 b, f32x4 c) {
  return __builtin_amdgcn_mfma_f32_16x16x32_f16(a, b, c, 0, 0, 0);
}

static __device__ __forceinline__ void gload16(const void* g, void* l) {
  __builtin_amdgcn_global_load_lds(
      (const __attribute__((address_space(1))) unsigned int*)g,
      (__attribute__((address_space(3))) unsigned int*)l, 16, 0, 0);
}

// -------------- prep: x -> xt[p][c] fp16, weights -> fp16 ------------------
__global__ __launch_bounds__(256) void k_prep(
    const float* __restrict__ x, f16* __restrict__ xt,
    const float* __restrict__ wpw, const float* __restrict__ wlin,
    f16* __restrict__ wpw_h, f16* __restrict__ wlin_h,
    int* __restrict__ kmax_bits) {
  __shared__ float t[32][33];
  int b = blockIdx.x;
  if (b < 1024) {
    int bc = b >> 7;     // 8 channel tiles of 32
    int bp = b & 127;    // 128 pixel tiles of 32
    int tx = threadIdx.x & 31, ty = threadIdx.x >> 5;  // ty 0..7
#pragma unroll
    for (int i = 0; i < 4; i++) {
      int c = bc * 32 + ty + i * 8;
      t[ty + i * 8][tx] = x[c * HW + bp * 32 + tx];
    }
    __syncthreads();
#pragma unroll
    for (int i = 0; i < 4; i++) {
      int p = bp * 32 + ty + i * 8;
      xt[p * NC + bc * 32 + tx] = (f16)t[tx][ty + i * 8];
    }
  } else {
    int i = (b - 1024) * 256 + threadIdx.x;  // 32768 threads
    if (i < 8) kmax_bits[i] = 0;             // init for k_norms' atomicMax
    for (int idx = i; idx < 3 * NC * NC; idx += 32768)
      wpw_h[idx] = (f16)wpw[idx];
    for (int idx = i; idx < NC * NC; idx += 32768)
      wlin_h[idx] = (f16)wlin[idx];
  }
}

// ------------------- GEMM1: qkv = Wpw[768,256] * x  (+bias) ----------------
__global__ __launch_bounds__(256) void k_gemm_qkv(
    const f16* __restrict__ w, const f16* __restrict__ xt,
    const float* __restrict__ bias, float* __restrict__ out) {
  int bm = blockIdx.x >> 6;   // 12
  int bn = blockIdx.x & 63;   // 64
  int wave = threadIdx.x >> 6, lane = threadIdx.x & 63;
  int r = lane & 15, g = lane >> 4;
  int m_row = bm * 64 + wave * 16 + r;
  int n0 = bn * 64;
  f32x4 acc[4] = {};
  for (int kk = 0; kk < NC; kk += 32) {
    f16x8 a = *(const f16x8*)&w[m_row * NC + kk + g * 8];
#pragma unroll
    for (int nt = 0; nt < 4; nt++) {
      f16x8 b = *(const f16x8*)&xt[(n0 + nt * 16 + r) * NC + kk + g * 8];
      acc[nt] = mfma16(a, b, acc[nt]);
    }
  }
  int mbase = bm * 64 + wave * 16 + g * 4;
  float bj[4];
#pragma unroll
  for (int j = 0; j < 4; j++) bj[j] = bias[mbase + j];
#pragma unroll
  for (int nt = 0; nt < 4; nt++)
#pragma unroll
    for (int j = 0; j < 4; j++)
      out[(mbase + j) * HW + n0 + nt * 16 + r] = acc[nt][j] + bj[j];
}

// ------------------- depthwise 11x11, pad 5, groups=768 --------------------
// q is pre-scaled by (1/temp)*log2(e) so softmax runs natively base-2.
__global__ __launch_bounds__(256) void k_dwconv(
    const float* __restrict__ qkv, const float* __restrict__ wdw,
    const float* __restrict__ bdw, f16* __restrict__ q_nm,
    f16* __restrict__ k_nm, f16* __restrict__ v_cm) {
  __shared__ float img[74 * 74];
  __shared__ float wgt[121];
  int c = blockIdx.x;
  int tid = threadIdx.x;
  for (int i = tid; i < 74 * 74; i += 256) {
    int row = i / 74, col = i - row * 74;
    int y = row - 5, xx = col - 5;
    img[i] = ((unsigned)y < 64u && (unsigned)xx < 64u) ? qkv[c * HW + y * 64 + xx]
                                                       : 0.f;
  }
  for (int i = tid; i < 121; i += 256) wgt[i] = wdw[c * 121 + i];
  __syncthreads();
  float bias = bdw[c];
#pragma unroll
  for (int it = 0; it < 2; it++) {
    int gi = it * 256 + tid;
    int px0 = gi * 8;
    int y = px0 >> 6, x0 = px0 & 63;
    float acc[8] = {};
#pragma unroll
    for (int ky = 0; ky < 11; ky++) {
      const float* rp = &img[(y + ky) * 74 + x0];
      float rv[18];
#pragma unroll
      for (int t = 0; t < 18; t++) rv[t] = rp[t];
#pragma unroll
      for (int kx = 0; kx < 11; kx++) {
        float wv = wgt[ky * 11 + kx];
#pragma unroll
        for (int p = 0; p < 8; p++) acc[p] = fmaf(rv[kx + p], wv, acc[p]);
      }
    }
    if (c < 256) {
      int h = c >> 5, d = c & 31;
#pragma unroll
      for (int p = 0; p < 8; p++)
        q_nm[(h * HW + px0 + p) * 32 + d] =
            (f16)((acc[p] + bias) * 0.28853900817779268f);  // 0.2*log2(e)
    } else if (c < 512) {
      int cc = c - 256;
      int h = cc >> 5, d = cc & 31;
#pragma unroll
      for (int p = 0; p < 8; p++)
        k_nm[(h * HW + px0 + p) * 32 + d] = (f16)(acc[p] + bias);
    } else {
      int cc = c - 512;
#pragma unroll
      for (int p = 0; p < 8; p++)
        v_cm[cc * HW + px0 + p] = (f16)(acc[p] + bias);
    }
  }
}

// ---------------- norms: ||q_row|| per row, max ||k_row|| per head ---------
__global__ __launch_bounds__(256) void k_norms(
    const f16* __restrict__ q_nm, const f16* __restrict__ k_nm,
    float* __restrict__ q_bound, int* __restrict__ kmax_bits) {
  __shared__ float red[256];
  int b = blockIdx.x, t = threadIdx.x;
  const f16* src = (b < 128) ? q_nm : k_nm;
  int row = ((b & 127) * 256) + t;
  const f16x8* p = (const f16x8*)&src[row * 32];
  float s = 0.f;
#pragma unroll
  for (int i = 0; i < 4; i++) {
    f16x8 v = p[i];
#pragma unroll
    for (int j = 0; j < 8; j++) {
      float f = (float)v[j];
      s = fmaf(f, f, s);
    }
  }
  float nrm = sqrtf(s);
  if (b < 128) {
    q_bound[row] = nrm;
  } else {
    red[t] = nrm;
    __syncthreads();
    for (int off = 128; off > 0; off >>= 1) {
      if (t < off) red[t] = fmaxf(red[t], red[t + off]);
      __syncthreads();
    }
    if (t == 0) atomicMax(&kmax_bits[row >> 12], __float_as_int(red[0]));
  }
}

// ----------------------------- flash attention -----------------------------
// Block = 512 threads = 8 waves; q-tile = 128 rows (wave wv owns rows
// [qt*128+wv*16,+16) x ALL 4096 keys). K/V staged in LDS, 64-key chunks,
// 4-deep buffers, counted-vmcnt pipeline (m201 pattern):
//   per chunk t: issue gload_lds for chunk t+2 (1 instr/wave) ->
//   s_waitcnt vmcnt(2) (own chunk-t loads landed) -> raw s_barrier
//   (=> ALL waves' chunk-t loads landed) -> compute chunk t from LDS.
// Never vmcnt(0) in the loop; one barrier per chunk. Waves 0-3 stage K,
// 4-7 stage V. K LDS [key][d] with 16B-slot XOR swizzle slot^=(key>>3)&3
// (both-sides: pre-swizzled global src, swizzled read) -> 2-way (free).
// V LDS [d][key] with R7's verified slot^=(d&7) swizzle.
// Fixed-shift softmax: P = exp2(s - C_row), -C in score-MFMA C-operand
// (Cauchy-Schwarz bound, P <= 2^13.9 f16-safe, 2^C cancels in O/L).
// Scores transposed: S^T = mfma(A=K row-permuted pr(i)=8*(i>>2)+(i&3), B=Q)
// so score C/D layout == PV A-fragment layout; P never leaves registers.
// h = bid&7: each XCD serves one head (512KB L2-resident).
__global__ __launch_bounds__(512, 2) void k_attn(
    const f16* __restrict__ q_nm, const f16* __restrict__ k_nm,
    const f16* __restrict__ v_cm, const float* __restrict__ q_bound,
    const int* __restrict__ kmax_bits, f16* __restrict__ newx) {
  __shared__ f16 lds_k[4][2048];  // 4 x 4KB: [key 0..63][d 0..31], swizzled
  __shared__ f16 lds_v[4][2048];  // 4 x 4KB: [d 0..31][key 0..63], swizzled
  int h = blockIdx.x & 7;    // head-affine swizzle
  int qt = blockIdx.x >> 3;  // 32 q tiles of 128 rows
  int tid = threadIdx.x;
  int wv = tid >> 6, lane = tid & 63;
  int r = lane & 15, g = lane >> 4;
  int n_base = qt * 128 + wv * 16;
  const f16* qh = q_nm + h * (HW * 32);
  const f16* kh = k_nm + h * (HW * 32);
  const f16* vh = v_cm + h * (32 * HW);

  f16x8 bq = *(const f16x8*)&qh[(n_base + r) * 32 + g * 8];
  float kmax = __int_as_float(kmax_bits[h]);
  float mC = 13.9f - q_bound[h * HW + n_base + r] * kmax;
  f32x4 cinit = {mC, mC, mC, mC};
  int pr = ((r & 12) << 1) | (r & 3);  // 8*(r>>2)+(r&3)
  f32x4 acc0 = {0.f, 0.f, 0.f, 0.f}, acc1 = {0.f, 0.f, 0.f, 0.f};
  float L = 0.f;

  // ---- staging addresses (chunk 0); 16B per lane per chunk ----
  // K (waves 0-3): lane l -> key kc=(wv&3)*16+(l>>2), slot (l&3)^((kc>>3)&3)
  int l4 = lane >> 2, l3 = lane & 3;
  int kc = (wv & 3) * 16 + l4;
  int ku = (kc >> 3) & 3;
  const f16* kg_base = kh + kc * 32 + (l3 ^ ku) * 8;
  // V (waves 4-7): t2 in 0..255 -> d=t2>>3, key-slot (t2&7)^(d&7)
  int t2v = (tid >= 256) ? tid - 256 : 0;
  int vd = t2v >> 3;
  int vkk = ((t2v & 7) ^ (vd & 7)) * 8;
  const f16* vg_base = vh + vd * HW + vkk;
  f16* kdst = &lds_k[0][0] + (wv & 3) * 512;   // + buf*2048
  f16* vdst = &lds_v[0][0] + (t2v >> 6) * 512; // wv-4

  // ---- consumer LDS byte offsets (loop-invariant) ----
  int u = r >> 2;
  int kslot = ((g ^ u) & 3) * 16;
  int ak0_off = pr * 64 + kslot;          // ks=0; ks=1: +2048
  int ak1_off = (pr + 4) * 64 + kslot;
  int vb_off0 = (r * 128 + g * 16) ^ ((r & 7) << 4);       // ks=0
  int vb_off1 = (r * 128 + 64 + g * 16) ^ ((r & 7) << 4);  // ks=1

  // ---- prologue: drain q/bound loads (modeled), prefetch chunks 0,1 ----
  __builtin_amdgcn_s_waitcnt(0);
  if (wv < 4) {
    gload16(kg_base, kdst);
    gload16(kg_base + 2048, kdst + 2048);
  } else {
    gload16(vg_base, vdst);
    gload16(vg_base + 64, vdst + 2048);
  }

  for (int t = 0; t < 64; ++t) {
    int c2 = (t + 2 <= 63) ? t + 2 : 63;  // clamp: redundant restage, unread
    int b2 = (t + 2) & 3;
    if (wv < 4)
      gload16(kg_base + c2 * 2048, kdst + b2 * 2048);
    else
      gload16(vg_base + c2 * 64, vdst + b2 * 2048);
    asm volatile("s_waitcnt vmcnt(2)" ::: "memory");
    __builtin_amdgcn_sched_barrier(0);
    __builtin_amdgcn_s_barrier();
    __builtin_amdgcn_sched_barrier(0);
    const char* kb = (const char*)&lds_k[t & 3][0];
    const char* vb = (const char*)&lds_v[t & 3][0];
#pragma unroll
    for (int ks = 0; ks < 2; ++ks) {
      f16x8 ak0 = *(const f16x8*)(kb + ks * 2048 + ak0_off);
      f16x8 ak1 = *(const f16x8*)(kb + ks * 2048 + ak1_off);
      f16x8 bv0 = *(const f16x8*)(vb + (ks ? vb_off1 : vb_off0));
      f16x8 bv1 = *(const f16x8*)(vb + (ks ? vb_off1 : vb_off0) + 2048);
      f32x4 s0 = mfma16(ak0, bq, cinit);
      f32x4 s1 = mfma16(ak1, bq, cinit);
      float p[8];
#pragma unroll
      for (int j = 0; j < 4; j++) {
        p[j] = EXP2(s0[j]);
        p[4 + j] = EXP2(s1[j]);
      }
      L += ((p[0] + p[1]) + (p[2] + p[3])) + ((p[4] + p[5]) + (p[6] + p[7]));
      union { hf16x2 h2[4]; f16x8 v; } uu;
#pragma unroll
      for (int j = 0; j < 4; j++)
        uu.h2[j] = __builtin_amdgcn_cvt_pkrtz(p[2 * j], p[2 * j + 1]);
      acc0 = mfma16(uu.v, bv0, acc0);
      acc1 = mfma16(uu.v, bv1, acc1);
    }
  }
  // ---- normalize and write own rows ----
  L += __shfl_xor(L, 16);
  L += __shfl_xor(L, 32);
  float il = 1.f / L;
#pragma unroll
  for (int j = 0; j < 4; j++) {
    float ilj = __shfl(il, 4 * g + j);  // 1/L for out-row n_base+4g+j
    int n = n_base + 4 * g + j;
    newx[n * NC + h * 32 + r] = (f16)(acc0[j] * ilj);
    newx[n * NC + h * 32 + 16 + r] = (f16)(acc1[j] * ilj);
  }
}

// ---------- GEMM2: out = relu(Wlin[256,256] * newx + b) + x ----------------
__global__ __launch_bounds__(256) void k_gemm_proj(
    const f16* __restrict__ w, const f16* __restrict__ nx,
    const float* __restrict__ bias, const float* __restrict__ x,
    float* __restrict__ out) {
  int bm = blockIdx.x >> 6;  // 4
  int bn = blockIdx.x & 63;  // 64
  int wave = threadIdx.x >> 6, lane = threadIdx.x & 63;
  int r = lane & 15, g = lane >> 4;
  int m_row = bm * 64 + wave * 16 + r;
  int n0 = bn * 64;
  f32x4 acc[4] = {};
  for (int kk = 0; kk < NC; kk += 32) {
    f16x8 a = *(const f16x8*)&w[m_row * NC + kk + g * 8];
#pragma unroll
    for (int nt = 0; nt < 4; nt++) {
      f16x8 b = *(const f16x8*)&nx[(n0 + nt * 16 + r) * NC + kk + g * 8];
      acc[nt] = mfma16(a, b, acc[nt]);
    }
  }
  int mbase = bm * 64 + wave * 16 + g * 4;
  float bj[4];
#pragma unroll
  for (int j = 0; j < 4; j++) bj[j] = bias[mbase + j];
#pragma unroll
  for (int nt = 0; nt < 4; nt++)
#pragma unroll
    for (int j = 0; j < 4; j++) {
      int m = mbase + j, n = n0 + nt * 16 + r;
      float v = fmaxf(acc[nt][j] + bj[j], 0.f) + x[m * HW + n];
      out[m * HW + n] = v;
    }
}

// ---------------------------------------------------------------------------
extern "C" void kernel_launch(void* const* d_in, const int* in_sizes, int n_in,
                              void* d_out, int out_size, void* d_ws,
                              size_t ws_size, hipStream_t stream) {
  const float* x = (const float*)d_in[0];
  const float* w_pw = (const float*)d_in[1];
  const float* b_pw = (const float*)d_in[2];
  const float* w_dw = (const float*)d_in[3];
  const float* b_dw = (const float*)d_in[4];
  const float* w_lin = (const float*)d_in[5];
  const float* b_lin = (const float*)d_in[6];
  float* out = (float*)d_out;

  char* ws = (char*)d_ws;
  f16* wpw_h = (f16*)(ws + 0);            // 768*256*2      = 393216
  f16* wlin_h = (f16*)(ws + 393216);      // 256*256*2      = 131072
  f16* xt = (f16*)(ws + 524288);          // 4096*256*2     = 2097152
  float* qkv = (float*)(ws + 2621440);    // 768*4096*4     = 12582912
  f16* q_nm = (f16*)(ws + 15204352);      // 8*4096*32*2    = 2097152
  f16* k_nm = (f16*)(ws + 17301504);      // 2097152
  f16* v_cm = (f16*)(ws + 19398656);      // 2097152
  f16* nx = (f16*)(ws + 21495808);        // 2097152
  float* q_bound = (float*)(ws + 23592960);  // 8*4096*4    = 131072
  int* kmax_bits = (int*)(ws + 23724032);    // 32 -> total 23724064 bytes

  k_prep<<<1152, 256, 0, stream>>>(x, xt, w_pw, w_lin, wpw_h, wlin_h,
                                   kmax_bits);
  k_gemm_qkv<<<768, 256, 0, stream>>>(wpw_h, xt, b_pw, qkv);
  k_dwconv<<<768, 256, 0, stream>>>(qkv, w_dw, b_dw, q_nm, k_nm, v_cm);
  k_norms<<<256, 256, 0, stream>>>(q_nm, k_nm, q_bound, kmax_bits);
  k_attn<<<256, 512, 0, stream>>>(q_nm, k_nm, v_cm, q_bound, kmax_bits, nx);
  k_gemm_proj<<<256, 256, 0, stream>>>(wlin_h, nx, b_lin, x, out);
}